// Round 5
// baseline (699.422 us; speedup 1.0000x reference)
//
#include <hip/hip_runtime.h>
#include <hip/hip_fp16.h>

#define NN 50000   // nodes
#define NE 100000  // edges
#define NB 512     // graphs
// H = 64, F_NODE = 16, F_EDGE = 8, T = 3

typedef _Float16 f16x8 __attribute__((ext_vector_type(8)));
typedef _Float16 f16x4 __attribute__((ext_vector_type(4)));
typedef float f32x4  __attribute__((ext_vector_type(4)));
typedef float f32x16 __attribute__((ext_vector_type(16)));

__device__ __forceinline__ float sigm(float v) { return 1.0f / (1.0f + __expf(-v)); }
__device__ __forceinline__ float tanh_fast(float v) {
    float e = __expf(-2.0f * fabsf(v));
    float t = (1.0f - e) / (1.0f + e);
    return v < 0.f ? -t : t;
}

__global__ void fill0_kernel(float4* __restrict__ p, int n4)
{
    int i = blockIdx.x * 256 + threadIdx.x;
    const int stride = gridDim.x * 256;
    for (; i < n4; i += stride) p[i] = make_float4(0.f, 0.f, 0.f, 0.f);
}

// x[n][h] = node_features[n] . Win[h] + bin[h]; also write f16 copy xh
__global__ __launch_bounds__(256) void node_in_kernel(
    const float* __restrict__ nf, const float* __restrict__ Win,
    const float* __restrict__ bin_, float* __restrict__ x, __half* __restrict__ xh)
{
    int idx = blockIdx.x * 256 + threadIdx.x;
    if (idx >= NN * 64) return;
    int n = idx >> 6, h = idx & 63;
    float acc = bin_[h];
    #pragma unroll
    for (int f = 0; f < 16; f++) acc += nf[n * 16 + f] * Win[h * 16 + f];
    x[idx] = acc;
    xh[idx] = __float2half(acc);
}

// ehh[e][k] = f16(relu(edge_features[e] . We1[k] + be1[k]))
__global__ __launch_bounds__(256) void edge_l1_kernel(
    const float* __restrict__ ef, const float* __restrict__ We1,
    const float* __restrict__ be1, __half* __restrict__ ehh)
{
    int idx = blockIdx.x * 256 + threadIdx.x;
    if (idx >= NE * 64) return;
    int e = idx >> 6, k = idx & 63;
    float acc = be1[k];
    #pragma unroll
    for (int f = 0; f < 8; f++) acc += ef[e * 8 + f] * We1[k * 8 + f];
    ehh[idx] = __float2half(fmaxf(acc, 0.0f));
}

// Pack We2 (+ be2 as kt 256..259) for 32x32x16 B-frags, lane-sequential:
// half index = kt*1024 + nt*512 + hi*256 + n*8 + i  <->  B[p = kt*16 + hi*8 + i][col = nt*32+n]
__global__ __launch_bounds__(256) void pack_b32_kernel(
    const float* __restrict__ We2, const float* __restrict__ be2,
    __half* __restrict__ Bp)
{
    int idx = blockIdx.x * 256 + threadIdx.x;
    if (idx >= 260 * 1024) return;
    int i  = idx & 7;
    int n  = (idx >> 3) & 31;
    int hi = (idx >> 8) & 1;
    int nt = (idx >> 9) & 1;
    int kt = idx >> 10;
    int p  = kt * 16 + hi * 8 + i;
    int col = nt * 32 + n;
    float v;
    if (p < 4096) {
        int j = p >> 6, k = p & 63;
        v = We2[((size_t)(col * 64 + j)) * 64 + k];
    } else {
        v = be2[col * 64 + (p - 4096)];
    }
    Bp[idx] = __float2half(v);
}

// Pack GRU weights into f16 B-frag layout WG[kt][nt][n][kk] (16x16x32 shape)
__global__ __launch_bounds__(256) void pack_gru_kernel(
    const float* __restrict__ Wih, const float* __restrict__ Whh,
    __half* __restrict__ WG)
{
    int idx = blockIdx.x * 256 + threadIdx.x;   // 2*24*16*32 = 24576
    if (idx >= 24576) return;
    int kk = idx & 31;
    int n  = (idx >> 5) & 15;
    int nt = (idx >> 9) % 24;
    int kt = (idx >> 9) / 24;
    int k = kt * 32 + kk;
    int col192 = (nt % 12) * 16 + n;
    int gate = col192 >> 6, h = col192 & 63;
    const float* src = (nt < 12) ? Wih : Whh;
    WG[idx] = __float2half(src[((size_t)(gate * 64 + h)) * 64 + k]);
}

// Message GEMM v5: single-wave blocks, 128 edges/wave (mt=4), 32x32x16 MFMA.
// B staged in 32 KB LDS chunks; 50.7 KB LDS total -> 3 blocks/CU, 782 blocks ~ balanced.
__global__ __launch_bounds__(64, 1) void msg_kernel(
    const __half* __restrict__ xh, const __half* __restrict__ ehh,
    const __half* __restrict__ Bp,
    const int* __restrict__ Esrc, const int* __restrict__ Etgt,
    float* __restrict__ agg)
{
    __shared__ __attribute__((aligned(16))) __half xs[128 * 72];   // 18.0 KB
    __shared__ __attribute__((aligned(16))) __half bst[16 * 1024]; // 32 KB
    __shared__ int tgt_s[128];
    const int lane = threadIdx.x;
    const int e0 = blockIdx.x * 128;
    const int n32 = lane & 31, hi = lane >> 5;

    // stage 128 gathered f16 source rows (2 per thread)
    #pragma unroll
    for (int rr = 0; rr < 2; rr++) {
        const int row = rr * 64 + lane;
        const int e = e0 + row;
        const bool ok = (e < NE);
        const int src = ok ? Esrc[e] : 0;
        tgt_s[row] = ok ? Etgt[e] : -1;
        const uint4* xsrc = (const uint4*)(xh + (size_t)src * 64);
        #pragma unroll
        for (int i = 0; i < 8; i++) {
            uint4 v = ok ? xsrc[i] : make_uint4(0, 0, 0, 0);
            *(uint4*)(&xs[row * 72 + i * 8]) = v;
        }
    }

    // per-lane eh cache: ehc[mt][c4] = eh[edge][c4*16 + hi*8 .. +8] as 4x half2
    __half2 ehc[4][4][4];
    #pragma unroll
    for (int mt = 0; mt < 4; mt++) {
        const int e = e0 + mt * 32 + n32;
        if (e < NE) {
            #pragma unroll
            for (int c4 = 0; c4 < 4; c4++) {
                union { uint4 u; __half2 h[4]; } u;
                u.u = *(const uint4*)(ehh + (size_t)e * 64 + c4 * 16 + hi * 8);
                #pragma unroll
                for (int q = 0; q < 4; q++) ehc[mt][c4][q] = u.h[q];
            }
        } else {
            __half2 z = __half2half2(__float2half(0.f));
            #pragma unroll
            for (int c4 = 0; c4 < 4; c4++)
                #pragma unroll
                for (int q = 0; q < 4; q++) ehc[mt][c4][q] = z;
        }
    }

    f32x16 acc[4][2];
    #pragma unroll
    for (int a = 0; a < 4; a++)
        #pragma unroll
        for (int b = 0; b < 2; b++)
            #pragma unroll
            for (int q = 0; q < 16; q++) acc[a][b][q] = 0.f;

    const __half* blane = bst + hi * 256 + n32 * 8;

    #pragma unroll 1
    for (int c = 0; c < 17; c++) {
        const int niter = (c < 16) ? 32 : 8;   // uint4 rounds of 64 lanes (16 or 4 kt)
        __syncthreads();
        {
            const __half* gsrc = Bp + (size_t)c * 16384;
            for (int i = 0; i < niter; i++)
                *(uint4*)(bst + (size_t)(i * 64 + lane) * 8) =
                    *(const uint4*)(gsrc + (size_t)(i * 64 + lane) * 8);
        }
        __syncthreads();

        if (c < 16) {
            f16x4 xr4[4];
            #pragma unroll
            for (int mt = 0; mt < 4; mt++)
                xr4[mt] = *(const f16x4*)(xs + (mt * 32 + n32) * 72 + c * 4);
            #pragma unroll
            for (int u = 0; u < 16; u++) {
                f16x8 b0 = *(const f16x8*)(blane + u * 1024);
                f16x8 b1 = *(const f16x8*)(blane + u * 1024 + 512);
                const int c4 = u & 3;
                const int jq = u >> 2;
                #pragma unroll
                for (int mt = 0; mt < 4; mt++) {
                    union { f16x4 v; __half h[4]; } xu; xu.v = xr4[mt];
                    __half2 xv2 = __half2half2(xu.h[jq]);
                    union { __half2 h[4]; f16x8 v; } a;
                    #pragma unroll
                    for (int q = 0; q < 4; q++) a.h[q] = __hmul2(xv2, ehc[mt][c4][q]);
                    acc[mt][0] = __builtin_amdgcn_mfma_f32_32x32x16_f16(a.v, b0, acc[mt][0], 0, 0, 0);
                    acc[mt][1] = __builtin_amdgcn_mfma_f32_32x32x16_f16(a.v, b1, acc[mt][1], 0, 0, 0);
                }
            }
        } else {
            // bias kts 256..259: A = x[edge][jj] directly from xs
            #pragma unroll
            for (int u = 0; u < 4; u++) {
                f16x8 b0 = *(const f16x8*)(blane + u * 1024);
                f16x8 b1 = *(const f16x8*)(blane + u * 1024 + 512);
                #pragma unroll
                for (int mt = 0; mt < 4; mt++) {
                    f16x8 a = *(const f16x8*)(xs + (mt * 32 + n32) * 72 + u * 16 + hi * 8);
                    acc[mt][0] = __builtin_amdgcn_mfma_f32_32x32x16_f16(a, b0, acc[mt][0], 0, 0, 0);
                    acc[mt][1] = __builtin_amdgcn_mfma_f32_32x32x16_f16(a, b1, acc[mt][1], 0, 0, 0);
                }
            }
        }
    }

    // C/D 32x32 layout: col = lane&31, row = (reg&3) + 8*(reg>>2) + 4*hi
    #pragma unroll
    for (int mt = 0; mt < 4; mt++) {
        #pragma unroll
        for (int r = 0; r < 16; r++) {
            const int rowe = (r & 3) + 8 * (r >> 2) + 4 * hi;
            const int t = tgt_s[mt * 32 + rowe];
            if (t >= 0) {
                atomicAdd(agg + (size_t)t * 64 + n32, acc[mt][0][r]);
                atomicAdd(agg + (size_t)t * 64 + 32 + n32, acc[mt][1][r]);
            }
        }
    }
}

// GRU v3: block = 64 nodes. Fully coalesced global I/O via LDS staging/transpose.
// MFMA (16x16x32): wave = 16 nodes x 384 gate-cols. Wave-local LDS rows -> no extra syncs.
__global__ __launch_bounds__(256, 2) void gru_kernel(
    const float* __restrict__ agg, float* __restrict__ x, __half* __restrict__ xh,
    const __half* __restrict__ WG,
    const float* __restrict__ bih, const float* __restrict__ bhh)
{
    __shared__ __attribute__((aligned(16))) __half wlds[24576];   // 48 KB
    __shared__ __attribute__((aligned(16))) __half aggh[64 * 72]; // 9 KB
    __shared__ __attribute__((aligned(16))) float xbuf[64 * 68];  // 17 KB
    const int tid = threadIdx.x;
    const int node0 = blockIdx.x * 64;

    {   // stage gate weights (48 KB)
        const uint4* src = (const uint4*)WG;
        uint4* dst = (uint4*)wlds;
        #pragma unroll
        for (int i = 0; i < 12; i++) dst[i * 256 + tid] = src[i * 256 + tid];
    }
    // stage agg (f32->f16) and x (f32), coalesced float4
    #pragma unroll
    for (int i = 0; i < 4; i++) {
        int idx4 = i * 256 + tid;           // 1024 = 64 nodes * 16 float4
        int nl = idx4 >> 4, c4 = idx4 & 15;
        int node = node0 + nl;
        float4 a = make_float4(0.f, 0.f, 0.f, 0.f);
        float4 xv = make_float4(0.f, 0.f, 0.f, 0.f);
        if (node < NN) {
            a  = *(const float4*)(agg + (size_t)node * 64 + c4 * 4);
            xv = *(const float4*)(x   + (size_t)node * 64 + c4 * 4);
        }
        __half2* ah = (__half2*)(aggh + nl * 72 + c4 * 4);
        ah[0] = __floats2half2_rn(a.x, a.y);
        ah[1] = __floats2half2_rn(a.z, a.w);
        *(float4*)(xbuf + nl * 68 + c4 * 4) = xv;
    }
    __syncthreads();

    const int w = tid >> 6, lane = tid & 63, m = lane & 15, quad = lane >> 4;
    const int nl_a = w * 16 + m;

    f16x8 a_agg[2], a_x[2];
    #pragma unroll
    for (int kt = 0; kt < 2; kt++) {
        const int koff = kt * 32 + quad * 8;
        a_agg[kt] = *(const f16x8*)(aggh + nl_a * 72 + koff);
        const float* xp = xbuf + nl_a * 68 + koff;
        union { __half2 h[4]; f16x8 v; } u;
        u.h[0] = __floats2half2_rn(xp[0], xp[1]);
        u.h[1] = __floats2half2_rn(xp[2], xp[3]);
        u.h[2] = __floats2half2_rn(xp[4], xp[5]);
        u.h[3] = __floats2half2_rn(xp[6], xp[7]);
        a_x[kt] = u.v;
    }

    f32x4 acc[24];
    #pragma unroll
    for (int nt = 0; nt < 24; nt++)
        #pragma unroll
        for (int q = 0; q < 4; q++) acc[nt][q] = 0.f;

    #pragma unroll
    for (int kt = 0; kt < 2; kt++) {
        #pragma unroll
        for (int nt = 0; nt < 24; nt++) {
            f16x8 b = *(const f16x8*)(wlds + (kt * 24 + nt) * 512 + m * 32 + quad * 8);
            acc[nt] = __builtin_amdgcn_mfma_f32_16x16x32_f16(
                (nt < 12) ? a_agg[kt] : a_x[kt], b, acc[nt], 0, 0, 0);
        }
    }

    // gate math; write xn back into xbuf (wave-local rows; xold read first)
    #pragma unroll
    for (int t = 0; t < 4; t++) {
        const int h = t * 16 + m;
        const float bir = bih[h], biz = bih[64 + h], bin = bih[128 + h];
        const float bhr = bhh[h], bhz = bhh[64 + h], bhn = bhh[128 + h];
        #pragma unroll
        for (int r = 0; r < 4; r++) {
            const int nl = w * 16 + quad * 4 + r;
            float ir  = acc[t][r]      + bir;
            float iz  = acc[4 + t][r]  + biz;
            float in_ = acc[8 + t][r]  + bin;
            float hr  = acc[12 + t][r] + bhr;
            float hz  = acc[16 + t][r] + bhz;
            float hn  = acc[20 + t][r] + bhn;
            float rg = sigm(ir + hr);
            float z  = sigm(iz + hz);
            float n  = tanh_fast(in_ + rg * hn);
            float xold = xbuf[nl * 68 + h];
            xbuf[nl * 68 + h] = (1.0f - z) * n + z * xold;
        }
    }
    __syncthreads();

    // coalesced writeout of x (float4) and xh (8 halfs)
    #pragma unroll
    for (int i = 0; i < 4; i++) {
        int idx4 = i * 256 + tid;
        int nl = idx4 >> 4, c4 = idx4 & 15;
        int node = node0 + nl;
        if (node < NN) {
            float4 v = *(const float4*)(xbuf + nl * 68 + c4 * 4);
            *(float4*)(x + (size_t)node * 64 + c4 * 4) = v;
        }
    }
    #pragma unroll
    for (int i = 0; i < 2; i++) {
        int idx8 = i * 256 + tid;           // 512 = 64 nodes * 8 groups
        int nl = idx8 >> 3, c8 = idx8 & 7;
        int node = node0 + nl;
        if (node < NN) {
            const float* xp = xbuf + nl * 68 + c8 * 8;
            union { __half2 h[4]; uint4 u; } u;
            u.h[0] = __floats2half2_rn(xp[0], xp[1]);
            u.h[1] = __floats2half2_rn(xp[2], xp[3]);
            u.h[2] = __floats2half2_rn(xp[4], xp[5]);
            u.h[3] = __floats2half2_rn(xp[6], xp[7]);
            *(uint4*)(xh + (size_t)node * 64 + c8 * 8) = u.u;
        }
    }
}

// out[n] = x[n].Wout + bout; pooled[batch[n]] += out[n]
__global__ __launch_bounds__(256) void pool_kernel(
    const float* __restrict__ x, const float* __restrict__ Wout,
    const float* __restrict__ bout, const int* __restrict__ batch,
    float* __restrict__ out)
{
    const int node = blockIdx.x * 256 + threadIdx.x;
    if (node >= NN) return;
    float acc = bout[0];
    const float4* xp = (const float4*)(x + (size_t)node * 64);
    #pragma unroll
    for (int i = 0; i < 16; i++) {
        float4 v = xp[i];
        acc += v.x * Wout[4*i] + v.y * Wout[4*i+1] + v.z * Wout[4*i+2] + v.w * Wout[4*i+3];
    }
    atomicAdd(out + batch[node], acc);
}

extern "C" void kernel_launch(void* const* d_in, const int* in_sizes, int n_in,
                              void* d_out, int out_size, void* d_ws, size_t ws_size,
                              hipStream_t stream)
{
    const float* nf   = (const float*)d_in[0];
    const float* ef   = (const float*)d_in[1];
    const int*   Esrc = (const int*)  d_in[2];
    const int*   Etgt = (const int*)  d_in[3];
    const int*   bat  = (const int*)  d_in[4];
    const float* Win  = (const float*)d_in[5];
    const float* bin_ = (const float*)d_in[6];
    const float* We1  = (const float*)d_in[7];
    const float* be1  = (const float*)d_in[8];
    const float* We2  = (const float*)d_in[9];
    const float* be2  = (const float*)d_in[10];
    const float* Wih  = (const float*)d_in[11];
    const float* bih  = (const float*)d_in[12];
    const float* Whh  = (const float*)d_in[13];
    const float* bhh  = (const float*)d_in[14];
    const float* Wout = (const float*)d_in[15];
    const float* bout = (const float*)d_in[16];

    char* ws = (char*)d_ws;
    float*  x   = (float*)(ws);                       // 12.8 MB
    float*  agg = (float*)(ws + 12800000);            // 12.8 MB
    __half* xh  = (__half*)(ws + 25600000);           // 6.4 MB
    __half* ehh = (__half*)(ws + 32000000);           // 12.8 MB
    __half* Bp  = (__half*)(ws + 44800000);           // 532,480 B
    __half* WG  = (__half*)(ws + 45400064);           // 49,152 B

    hipMemsetAsync(d_out, 0, NB * sizeof(float), stream);

    node_in_kernel<<<(NN * 64 + 255) / 256, 256, 0, stream>>>(nf, Win, bin_, x, xh);
    edge_l1_kernel<<<(NE * 64 + 255) / 256, 256, 0, stream>>>(ef, We1, be1, ehh);
    pack_b32_kernel<<<(260 * 1024 + 255) / 256, 256, 0, stream>>>(We2, be2, Bp);
    pack_gru_kernel<<<(24576 + 255) / 256, 256, 0, stream>>>(Wih, Whh, WG);

    for (int t = 0; t < 3; t++) {
        fill0_kernel<<<1024, 256, 0, stream>>>((float4*)agg, NN * 16);
        msg_kernel<<<(NE + 127) / 128, 64, 0, stream>>>(xh, ehh, Bp, Esrc, Etgt, agg);
        gru_kernel<<<(NN + 63) / 64, 256, 0, stream>>>(agg, x, xh, WG, bih, bhh);
    }

    pool_kernel<<<(NN + 255) / 256, 256, 0, stream>>>(x, Wout, bout, bat, (float*)d_out);
}

// Round 6
// 486.719 us; speedup vs baseline: 1.4370x; 1.4370x over previous
//
#include <hip/hip_runtime.h>
#include <hip/hip_fp16.h>

#define NN 50000   // nodes
#define NE 100000  // edges
#define NB 512     // graphs
// H = 64, F_NODE = 16, F_EDGE = 8, T = 3

typedef _Float16 f16x8 __attribute__((ext_vector_type(8)));
typedef _Float16 f16x4 __attribute__((ext_vector_type(4)));
typedef float f32x4  __attribute__((ext_vector_type(4)));
typedef float f32x16 __attribute__((ext_vector_type(16)));

__device__ __forceinline__ float sigm(float v) { return 1.0f / (1.0f + __expf(-v)); }
__device__ __forceinline__ float tanh_fast(float v) {
    float e = __expf(-2.0f * fabsf(v));
    float t = (1.0f - e) / (1.0f + e);
    return v < 0.f ? -t : t;
}

__global__ void fill0_kernel(float4* __restrict__ p, int n4)
{
    int i = blockIdx.x * 256 + threadIdx.x;
    const int stride = gridDim.x * 256;
    for (; i < n4; i += stride) p[i] = make_float4(0.f, 0.f, 0.f, 0.f);
}

// x[n][h] = node_features[n] . Win[h] + bin[h]; also write f16 copy xh
__global__ __launch_bounds__(256) void node_in_kernel(
    const float* __restrict__ nf, const float* __restrict__ Win,
    const float* __restrict__ bin_, float* __restrict__ x, __half* __restrict__ xh)
{
    int idx = blockIdx.x * 256 + threadIdx.x;
    if (idx >= NN * 64) return;
    int n = idx >> 6, h = idx & 63;
    float acc = bin_[h];
    #pragma unroll
    for (int f = 0; f < 16; f++) acc += nf[n * 16 + f] * Win[h * 16 + f];
    x[idx] = acc;
    xh[idx] = __float2half(acc);
}

// ehh[e][k] = f16(relu(edge_features[e] . We1[k] + be1[k]))
__global__ __launch_bounds__(256) void edge_l1_kernel(
    const float* __restrict__ ef, const float* __restrict__ We1,
    const float* __restrict__ be1, __half* __restrict__ ehh)
{
    int idx = blockIdx.x * 256 + threadIdx.x;
    if (idx >= NE * 64) return;
    int e = idx >> 6, k = idx & 63;
    float acc = be1[k];
    #pragma unroll
    for (int f = 0; f < 8; f++) acc += ef[e * 8 + f] * We1[k * 8 + f];
    ehh[idx] = __float2half(fmaxf(acc, 0.0f));
}

// Pack We2 (+ be2 as kt 256..259) for 32x32x16 B-frags, lane-sequential:
// half index = kt*1024 + nt*512 + hi*256 + n*8 + i  <->  B[p = kt*16 + hi*8 + i][col = nt*32+n]
__global__ __launch_bounds__(256) void pack_b32_kernel(
    const float* __restrict__ We2, const float* __restrict__ be2,
    __half* __restrict__ Bp)
{
    int idx = blockIdx.x * 256 + threadIdx.x;
    if (idx >= 260 * 1024) return;
    int i  = idx & 7;
    int n  = (idx >> 3) & 31;
    int hi = (idx >> 8) & 1;
    int nt = (idx >> 9) & 1;
    int kt = idx >> 10;
    int p  = kt * 16 + hi * 8 + i;
    int col = nt * 32 + n;
    float v;
    if (p < 4096) {
        int j = p >> 6, k = p & 63;
        v = We2[((size_t)(col * 64 + j)) * 64 + k];
    } else {
        v = be2[col * 64 + (p - 4096)];
    }
    Bp[idx] = __float2half(v);
}

// Pack GRU weights into f16 B-frag layout WG[kt][nt][n][kk] (16x16x32 shape)
__global__ __launch_bounds__(256) void pack_gru_kernel(
    const float* __restrict__ Wih, const float* __restrict__ Whh,
    __half* __restrict__ WG)
{
    int idx = blockIdx.x * 256 + threadIdx.x;   // 2*24*16*32 = 24576
    if (idx >= 24576) return;
    int kk = idx & 31;
    int n  = (idx >> 5) & 15;
    int nt = (idx >> 9) % 24;
    int kt = (idx >> 9) / 24;
    int k = kt * 32 + kk;
    int col192 = (nt % 12) * 16 + n;
    int gate = col192 >> 6, h = col192 & 63;
    const float* src = (nt < 12) ? Wih : Whh;
    WG[idx] = __float2half(src[((size_t)(gate * 64 + h)) * 64 + k]);
}

// Message GEMM v6: 2-wave blocks, 128 edges/wave (mt=4), 32x32x16 MFMA.
// B staged in 32 KB LDS chunks shared by both waves; each B-frag feeds 4 MFMAs.
// LDS 70.7 KB -> 2 blocks/CU (4 waves/CU); 391 blocks.
__global__ __launch_bounds__(128) void msg_kernel(
    const __half* __restrict__ xh, const __half* __restrict__ ehh,
    const __half* __restrict__ Bp,
    const int* __restrict__ Esrc, const int* __restrict__ Etgt,
    float* __restrict__ agg)
{
    __shared__ __attribute__((aligned(16))) __half xs[256 * 72];   // 36.9 KB
    __shared__ __attribute__((aligned(16))) __half bst[16 * 1024]; // 32 KB
    __shared__ int tgt_s[256];
    const int tid = threadIdx.x;
    const int e0 = blockIdx.x * 256;
    const int w = tid >> 6, lane = tid & 63;
    const int n32 = lane & 31, hi = lane >> 5;

    // stage 256 gathered f16 source rows (2 per thread)
    #pragma unroll
    for (int rr = 0; rr < 2; rr++) {
        const int row = rr * 128 + tid;
        const int e = e0 + row;
        const bool ok = (e < NE);
        const int src = ok ? Esrc[e] : 0;
        tgt_s[row] = ok ? Etgt[e] : -1;
        const uint4* xsrc = (const uint4*)(xh + (size_t)src * 64);
        #pragma unroll
        for (int i = 0; i < 8; i++) {
            uint4 v = ok ? xsrc[i] : make_uint4(0, 0, 0, 0);
            *(uint4*)(&xs[row * 72 + i * 8]) = v;
        }
    }

    // per-lane eh cache: ehc[mt][c4] = eh[edge][c4*16 + hi*8 .. +8] as 4x half2
    __half2 ehc[4][4][4];
    #pragma unroll
    for (int mt = 0; mt < 4; mt++) {
        const int e = e0 + w * 128 + mt * 32 + n32;
        if (e < NE) {
            #pragma unroll
            for (int c4 = 0; c4 < 4; c4++) {
                union { uint4 u; __half2 h[4]; } u;
                u.u = *(const uint4*)(ehh + (size_t)e * 64 + c4 * 16 + hi * 8);
                #pragma unroll
                for (int q = 0; q < 4; q++) ehc[mt][c4][q] = u.h[q];
            }
        } else {
            __half2 z = __half2half2(__float2half(0.f));
            #pragma unroll
            for (int c4 = 0; c4 < 4; c4++)
                #pragma unroll
                for (int q = 0; q < 4; q++) ehc[mt][c4][q] = z;
        }
    }

    f32x16 acc[4][2];
    #pragma unroll
    for (int a = 0; a < 4; a++)
        #pragma unroll
        for (int b = 0; b < 2; b++)
            #pragma unroll
            for (int q = 0; q < 16; q++) acc[a][b][q] = 0.f;

    const __half* blane = bst + hi * 256 + n32 * 8;
    const int rbase = w * 128;     // wave's xs row base

    #pragma unroll 1
    for (int c = 0; c < 17; c++) {
        const int niter = (c < 16) ? 16 : 4;   // uint4 rounds of 128 threads
        __syncthreads();
        {
            const __half* gsrc = Bp + (size_t)c * 16384;
            for (int i = 0; i < niter; i++)
                *(uint4*)(bst + (size_t)(i * 128 + tid) * 8) =
                    *(const uint4*)(gsrc + (size_t)(i * 128 + tid) * 8);
        }
        __syncthreads();

        if (c < 16) {
            f16x4 xr4[4];
            #pragma unroll
            for (int mt = 0; mt < 4; mt++)
                xr4[mt] = *(const f16x4*)(xs + (rbase + mt * 32 + n32) * 72 + c * 4);
            #pragma unroll
            for (int u = 0; u < 16; u++) {
                f16x8 b0 = *(const f16x8*)(blane + u * 1024);
                f16x8 b1 = *(const f16x8*)(blane + u * 1024 + 512);
                const int c4 = u & 3;
                const int jq = u >> 2;
                #pragma unroll
                for (int mt = 0; mt < 4; mt++) {
                    union { f16x4 v; __half h[4]; } xu; xu.v = xr4[mt];
                    __half2 xv2 = __half2half2(xu.h[jq]);
                    union { __half2 h[4]; f16x8 v; } a;
                    #pragma unroll
                    for (int q = 0; q < 4; q++) a.h[q] = __hmul2(xv2, ehc[mt][c4][q]);
                    acc[mt][0] = __builtin_amdgcn_mfma_f32_32x32x16_f16(a.v, b0, acc[mt][0], 0, 0, 0);
                    acc[mt][1] = __builtin_amdgcn_mfma_f32_32x32x16_f16(a.v, b1, acc[mt][1], 0, 0, 0);
                }
            }
        } else {
            // bias kts 256..259: A = x[edge][jj] directly from xs
            #pragma unroll
            for (int u = 0; u < 4; u++) {
                f16x8 b0 = *(const f16x8*)(blane + u * 1024);
                f16x8 b1 = *(const f16x8*)(blane + u * 1024 + 512);
                #pragma unroll
                for (int mt = 0; mt < 4; mt++) {
                    f16x8 a = *(const f16x8*)(xs + (rbase + mt * 32 + n32) * 72 + u * 16 + hi * 8);
                    acc[mt][0] = __builtin_amdgcn_mfma_f32_32x32x16_f16(a, b0, acc[mt][0], 0, 0, 0);
                    acc[mt][1] = __builtin_amdgcn_mfma_f32_32x32x16_f16(a, b1, acc[mt][1], 0, 0, 0);
                }
            }
        }
    }

    // C/D 32x32 layout: col = lane&31, row = (reg&3) + 8*(reg>>2) + 4*hi
    #pragma unroll
    for (int mt = 0; mt < 4; mt++) {
        #pragma unroll
        for (int r = 0; r < 16; r++) {
            const int rowe = (r & 3) + 8 * (r >> 2) + 4 * hi;
            const int t = tgt_s[rbase + mt * 32 + rowe];
            if (t >= 0) {
                atomicAdd(agg + (size_t)t * 64 + n32, acc[mt][0][r]);
                atomicAdd(agg + (size_t)t * 64 + 32 + n32, acc[mt][1][r]);
            }
        }
    }
}

// GRU v3: block = 64 nodes. Fully coalesced global I/O via LDS staging/transpose.
// MFMA (16x16x32): wave = 16 nodes x 384 gate-cols. Wave-local LDS rows -> no extra syncs.
__global__ __launch_bounds__(256, 2) void gru_kernel(
    const float* __restrict__ agg, float* __restrict__ x, __half* __restrict__ xh,
    const __half* __restrict__ WG,
    const float* __restrict__ bih, const float* __restrict__ bhh)
{
    __shared__ __attribute__((aligned(16))) __half wlds[24576];   // 48 KB
    __shared__ __attribute__((aligned(16))) __half aggh[64 * 72]; // 9 KB
    __shared__ __attribute__((aligned(16))) float xbuf[64 * 68];  // 17 KB
    const int tid = threadIdx.x;
    const int node0 = blockIdx.x * 64;

    {   // stage gate weights (48 KB)
        const uint4* src = (const uint4*)WG;
        uint4* dst = (uint4*)wlds;
        #pragma unroll
        for (int i = 0; i < 12; i++) dst[i * 256 + tid] = src[i * 256 + tid];
    }
    // stage agg (f32->f16) and x (f32), coalesced float4
    #pragma unroll
    for (int i = 0; i < 4; i++) {
        int idx4 = i * 256 + tid;           // 1024 = 64 nodes * 16 float4
        int nl = idx4 >> 4, c4 = idx4 & 15;
        int node = node0 + nl;
        float4 a = make_float4(0.f, 0.f, 0.f, 0.f);
        float4 xv = make_float4(0.f, 0.f, 0.f, 0.f);
        if (node < NN) {
            a  = *(const float4*)(agg + (size_t)node * 64 + c4 * 4);
            xv = *(const float4*)(x   + (size_t)node * 64 + c4 * 4);
        }
        __half2* ah = (__half2*)(aggh + nl * 72 + c4 * 4);
        ah[0] = __floats2half2_rn(a.x, a.y);
        ah[1] = __floats2half2_rn(a.z, a.w);
        *(float4*)(xbuf + nl * 68 + c4 * 4) = xv;
    }
    __syncthreads();

    const int w = tid >> 6, lane = tid & 63, m = lane & 15, quad = lane >> 4;
    const int nl_a = w * 16 + m;

    f16x8 a_agg[2], a_x[2];
    #pragma unroll
    for (int kt = 0; kt < 2; kt++) {
        const int koff = kt * 32 + quad * 8;
        a_agg[kt] = *(const f16x8*)(aggh + nl_a * 72 + koff);
        const float* xp = xbuf + nl_a * 68 + koff;
        union { __half2 h[4]; f16x8 v; } u;
        u.h[0] = __floats2half2_rn(xp[0], xp[1]);
        u.h[1] = __floats2half2_rn(xp[2], xp[3]);
        u.h[2] = __floats2half2_rn(xp[4], xp[5]);
        u.h[3] = __floats2half2_rn(xp[6], xp[7]);
        a_x[kt] = u.v;
    }

    f32x4 acc[24];
    #pragma unroll
    for (int nt = 0; nt < 24; nt++)
        #pragma unroll
        for (int q = 0; q < 4; q++) acc[nt][q] = 0.f;

    #pragma unroll
    for (int kt = 0; kt < 2; kt++) {
        #pragma unroll
        for (int nt = 0; nt < 24; nt++) {
            f16x8 b = *(const f16x8*)(wlds + (kt * 24 + nt) * 512 + m * 32 + quad * 8);
            acc[nt] = __builtin_amdgcn_mfma_f32_16x16x32_f16(
                (nt < 12) ? a_agg[kt] : a_x[kt], b, acc[nt], 0, 0, 0);
        }
    }

    // gate math; write xn back into xbuf (wave-local rows; xold read first)
    #pragma unroll
    for (int t = 0; t < 4; t++) {
        const int h = t * 16 + m;
        const float bir = bih[h], biz = bih[64 + h], bin = bih[128 + h];
        const float bhr = bhh[h], bhz = bhh[64 + h], bhn = bhh[128 + h];
        #pragma unroll
        for (int r = 0; r < 4; r++) {
            const int nl = w * 16 + quad * 4 + r;
            float ir  = acc[t][r]      + bir;
            float iz  = acc[4 + t][r]  + biz;
            float in_ = acc[8 + t][r]  + bin;
            float hr  = acc[12 + t][r] + bhr;
            float hz  = acc[16 + t][r] + bhz;
            float hn  = acc[20 + t][r] + bhn;
            float rg = sigm(ir + hr);
            float z  = sigm(iz + hz);
            float n  = tanh_fast(in_ + rg * hn);
            float xold = xbuf[nl * 68 + h];
            xbuf[nl * 68 + h] = (1.0f - z) * n + z * xold;
        }
    }
    __syncthreads();

    // coalesced writeout of x (float4) and xh (8 halfs)
    #pragma unroll
    for (int i = 0; i < 4; i++) {
        int idx4 = i * 256 + tid;
        int nl = idx4 >> 4, c4 = idx4 & 15;
        int node = node0 + nl;
        if (node < NN) {
            float4 v = *(const float4*)(xbuf + nl * 68 + c4 * 4);
            *(float4*)(x + (size_t)node * 64 + c4 * 4) = v;
        }
    }
    #pragma unroll
    for (int i = 0; i < 2; i++) {
        int idx8 = i * 256 + tid;           // 512 = 64 nodes * 8 groups
        int nl = idx8 >> 3, c8 = idx8 & 7;
        int node = node0 + nl;
        if (node < NN) {
            const float* xp = xbuf + nl * 68 + c8 * 8;
            union { __half2 h[4]; uint4 u; } u;
            u.h[0] = __floats2half2_rn(xp[0], xp[1]);
            u.h[1] = __floats2half2_rn(xp[2], xp[3]);
            u.h[2] = __floats2half2_rn(xp[4], xp[5]);
            u.h[3] = __floats2half2_rn(xp[6], xp[7]);
            *(uint4*)(xh + (size_t)node * 64 + c8 * 8) = u.u;
        }
    }
}

// out[n] = x[n].Wout + bout; pooled[batch[n]] += out[n]
__global__ __launch_bounds__(256) void pool_kernel(
    const float* __restrict__ x, const float* __restrict__ Wout,
    const float* __restrict__ bout, const int* __restrict__ batch,
    float* __restrict__ out)
{
    const int node = blockIdx.x * 256 + threadIdx.x;
    if (node >= NN) return;
    float acc = bout[0];
    const float4* xp = (const float4*)(x + (size_t)node * 64);
    #pragma unroll
    for (int i = 0; i < 16; i++) {
        float4 v = xp[i];
        acc += v.x * Wout[4*i] + v.y * Wout[4*i+1] + v.z * Wout[4*i+2] + v.w * Wout[4*i+3];
    }
    atomicAdd(out + batch[node], acc);
}

extern "C" void kernel_launch(void* const* d_in, const int* in_sizes, int n_in,
                              void* d_out, int out_size, void* d_ws, size_t ws_size,
                              hipStream_t stream)
{
    const float* nf   = (const float*)d_in[0];
    const float* ef   = (const float*)d_in[1];
    const int*   Esrc = (const int*)  d_in[2];
    const int*   Etgt = (const int*)  d_in[3];
    const int*   bat  = (const int*)  d_in[4];
    const float* Win  = (const float*)d_in[5];
    const float* bin_ = (const float*)d_in[6];
    const float* We1  = (const float*)d_in[7];
    const float* be1  = (const float*)d_in[8];
    const float* We2  = (const float*)d_in[9];
    const float* be2  = (const float*)d_in[10];
    const float* Wih  = (const float*)d_in[11];
    const float* bih  = (const float*)d_in[12];
    const float* Whh  = (const float*)d_in[13];
    const float* bhh  = (const float*)d_in[14];
    const float* Wout = (const float*)d_in[15];
    const float* bout = (const float*)d_in[16];

    char* ws = (char*)d_ws;
    float*  x   = (float*)(ws);                       // 12.8 MB
    float*  agg = (float*)(ws + 12800000);            // 12.8 MB
    __half* xh  = (__half*)(ws + 25600000);           // 6.4 MB
    __half* ehh = (__half*)(ws + 32000000);           // 12.8 MB
    __half* Bp  = (__half*)(ws + 44800000);           // 532,480 B
    __half* WG  = (__half*)(ws + 45400064);           // 49,152 B

    hipMemsetAsync(d_out, 0, NB * sizeof(float), stream);

    node_in_kernel<<<(NN * 64 + 255) / 256, 256, 0, stream>>>(nf, Win, bin_, x, xh);
    edge_l1_kernel<<<(NE * 64 + 255) / 256, 256, 0, stream>>>(ef, We1, be1, ehh);
    pack_b32_kernel<<<(260 * 1024 + 255) / 256, 256, 0, stream>>>(We2, be2, Bp);
    pack_gru_kernel<<<(24576 + 255) / 256, 256, 0, stream>>>(Wih, Whh, WG);

    for (int t = 0; t < 3; t++) {
        fill0_kernel<<<1024, 256, 0, stream>>>((float4*)agg, NN * 16);
        msg_kernel<<<(NE + 255) / 256, 128, 0, stream>>>(xh, ehh, Bp, Esrc, Etgt, agg);
        gru_kernel<<<(NN + 63) / 64, 256, 0, stream>>>(agg, x, xh, WG, bih, bhh);
    }

    pool_kernel<<<(NN + 255) / 256, 256, 0, stream>>>(x, Wout, bout, bat, (float*)d_out);
}